// Round 14
// baseline (1397.277 us; speedup 1.0000x reference)
//
#include <hip/hip_runtime.h>
#include <hip/hip_bf16.h>

#define NN 100000
#define HD 128
#define EE 1600000
#define BKT_SHIFT 6
#define NBKT 1563            // ceil(100000/64)
#define NTB (4 * NBKT)       // 6252 coarse buckets total
#define BCAP 1536            // fixed bucket capacity (Poisson λ=1024: max ~1158)
#define SCAT_B 256
#define ENC_B 512
#define PREP_B 768

typedef __hip_bfloat16 bf16;
typedef short short8 __attribute__((ext_vector_type(8)));
typedef float f32x4 __attribute__((ext_vector_type(4)));

__device__ inline float lo2f(unsigned u) { unsigned v = u << 16;        return __builtin_bit_cast(float, v); }
__device__ inline float hi2f(unsigned u) { unsigned v = u & 0xffff0000u; return __builtin_bit_cast(float, v); }
__device__ inline unsigned short f2bf_bits(float x) {
    bf16 b = __float2bfloat16(x);
    return *reinterpret_cast<unsigned short*>(&b);
}
__device__ inline f32x4 expand2(unsigned x, unsigned y) {
    return (f32x4){lo2f(x), hi2f(x), lo2f(y), hi2f(y)};
}

// ============================================= D2: scatter (blocks 0..SCAT_B) ∥ encoders
__global__ __launch_bounds__(1024) void scatter_enc_kernel(
    const int* __restrict__ ei_pp, const int* __restrict__ ei_dd,
    const int* __restrict__ ei_p2d,
    int* __restrict__ ccursor, unsigned* __restrict__ rec,
    const float* __restrict__ x_p, const float* __restrict__ w_p, const float* __restrict__ b_p,
    const float* __restrict__ x_d, const float* __restrict__ w_d, const float* __restrict__ b_d,
    bf16* __restrict__ Hp, bf16* __restrict__ Hd, int E, int n)
{
    __shared__ int lh[NTB];
    if ((int)blockIdx.x < SCAT_B) {
        // ---------------- scatter path: binned scatter with block reservation
        for (int i = threadIdx.x; i < NTB; i += 1024) lh[i] = 0;
        __syncthreads();
        const int total = 3 * E;
        const int chunk = (total + SCAT_B - 1) / SCAT_B;
        const int c0 = blockIdx.x * chunk;
        const int c1 = min(total, c0 + chunk);
        for (int gid = c0 + threadIdx.x; gid < c1; gid += 1024) {
            if (gid < E) {
                atomicAdd(&lh[0 * NBKT + (ei_pp[E + gid] >> BKT_SHIFT)], 1);
            } else if (gid < 2 * E) {
                atomicAdd(&lh[1 * NBKT + (ei_dd[gid] >> BKT_SHIFT)], 1);
            } else {
                int e = gid - 2 * E;
                atomicAdd(&lh[2 * NBKT + (ei_p2d[E + e] >> BKT_SHIFT)], 1);
                atomicAdd(&lh[3 * NBKT + (ei_p2d[e] >> BKT_SHIFT)], 1);
            }
        }
        __syncthreads();
        for (int i = threadIdx.x; i < NTB; i += 1024) {
            int c = lh[i];
            if (c) lh[i] = i * BCAP + atomicAdd(ccursor + i, c);
        }
        __syncthreads();
        for (int gid = c0 + threadIdx.x; gid < c1; gid += 1024) {
            if (gid < E) {
                int s = ei_pp[gid], d = ei_pp[E + gid];
                int pos = atomicAdd(&lh[0 * NBKT + (d >> BKT_SHIFT)], 1);
                rec[pos] = ((unsigned)(d & 63) << 17) | (unsigned)s;
            } else if (gid < 2 * E) {
                int e = gid - E;
                int s = ei_dd[e], d = ei_dd[E + e];
                int pos = atomicAdd(&lh[1 * NBKT + (d >> BKT_SHIFT)], 1);
                rec[pos] = ((unsigned)(d & 63) << 17) | (unsigned)s;
            } else {
                int e = gid - 2 * E;
                int sp = ei_p2d[e], sd = ei_p2d[E + e];
                int pos = atomicAdd(&lh[2 * NBKT + (sd >> BKT_SHIFT)], 1);
                rec[pos] = ((unsigned)(sd & 63) << 17) | (unsigned)sp;   // p2d
                pos = atomicAdd(&lh[3 * NBKT + (sp >> BKT_SHIFT)], 1);
                rec[pos] = ((unsigned)(sp & 63) << 17) | (unsigned)sd;   // d2p
            }
        }
    } else {
        // ---------------- encoder path: 8 nodes per block-iter (128 thr each)
        int eb  = blockIdx.x - SCAT_B;
        int sub = threadIdx.x >> 7;
        int j   = threadIdx.x & 127;
        for (int node = eb * 8 + sub; node < n; node += ENC_B * 8) {
            const float* xr = x_p + (size_t)node * 16;
            float acc = b_p[j];
#pragma unroll
            for (int k = 0; k < 16; ++k) acc += xr[k] * w_p[j * 16 + k];
            Hp[(size_t)node * HD + j] = __float2bfloat16(fmaxf(acc, 0.0f));
        }
        for (int node = eb * 8 + sub; node < n; node += ENC_B * 8) {
            const float* xr = x_d + (size_t)node * 8;
            float acc = b_d[j];
#pragma unroll
            for (int k = 0; k < 8; ++k) acc += xr[k] * w_d[j * 8 + k];
            Hd[(size_t)node * HD + j] = __float2bfloat16(fmaxf(acc, 0.0f));
        }
    }
}

// ============================================= D3: prep_w (blocks 0..PREP_B) ∥ fill_stats
__global__ __launch_bounds__(256) void fill_prep_kernel(
    const unsigned* __restrict__ rec, const int* __restrict__ ccursor,
    int* __restrict__ rowbeg, int* __restrict__ rowend, int* __restrict__ esrc,
    const float* __restrict__ ll, const float* __restrict__ lr,
    unsigned short* __restrict__ whi, unsigned short* __restrict__ wlo, int N)
{
    if ((int)blockIdx.x < PREP_B) {
        // ---------------- weight prep path (transposed, hi+lo bf16 split)
        int gid = blockIdx.x * 256 + threadIdx.x;
        if (gid >= 4 * 384 * 128) return;
        int cfg = gid / (384 * 128);
        int rem = gid - cfg * (384 * 128);
        int k = rem >> 7;
        int j = rem & 127;
        int l  = cfg >> 1;
        int ia = (cfg & 1) ? 1 : 0;
        int ib = (cfg & 1) ? 2 : 3;
        float v;
        if (k < 128)
            v = ll[((l * 4 + ia) * 128 + j) * 128 + k];
        else if (k < 256)
            v = ll[((l * 4 + ib) * 128 + j) * 128 + (k - 128)];
        else
            v = lr[((l * 4 + ia) * 128 + j) * 128 + (k - 256)]
              + lr[((l * 4 + ib) * 128 + j) * 128 + (k - 256)];
        unsigned short hb = f2bf_bits(v);
        float hf = hi2f((unsigned)hb << 16);
        unsigned short lb = f2bf_bits(v - hf);
        size_t o = (size_t)cfg * (128 * 384) + (size_t)j * 384 + k;
        whi[o] = hb;
        wlo[o] = lb;
    } else {
        // ---------------- fine fill path, one block per bucket
        int tb = blockIdx.x - PREP_B;
        int type = tb / NBKT;
        int bkt  = tb - type * NBKT;
        int base = tb * BCAP;
        int cnt  = ccursor[tb];
        __shared__ int lcnt[64];
        __shared__ int lcur[64];
        if (threadIdx.x < 64) lcnt[threadIdx.x] = 0;
        __syncthreads();
        for (int i = threadIdx.x; i < cnt; i += 256)
            atomicAdd(&lcnt[rec[base + i] >> 17], 1);
        __syncthreads();
        if (threadIdx.x == 0) {
            int run = base;
            for (int j = 0; j < 64; ++j) { lcur[j] = run; run += lcnt[j]; }
        }
        __syncthreads();
        if (threadIdx.x < 64) {
            int node = (bkt << BKT_SHIFT) + threadIdx.x;
            if (node < N) {
                rowbeg[(size_t)type * N + node] = lcur[threadIdx.x];
                rowend[(size_t)type * N + node] = lcur[threadIdx.x] + lcnt[threadIdx.x];
            }
        }
        __syncthreads();
        for (int i = threadIdx.x; i < cnt; i += 256) {
            unsigned p = rec[base + i];
            int pos = atomicAdd(&lcur[p >> 17], 1);
            esrc[pos] = (int)(p & 0x1FFFFu);
        }
    }
}

// ============================================= aggregation body (per-node wave gather)
__device__ __forceinline__ void gather_reduce_store(
    const bf16* __restrict__ src, const int* __restrict__ esrc,
    int beg, int end, int g, int c8, int lane, bf16* __restrict__ outrow)
{
    float iv = 1.0f / fmaxf((float)(end - beg), 1.0f);
    f32x4 acc0 = {0.f, 0.f, 0.f, 0.f}, acc1 = {0.f, 0.f, 0.f, 0.f};
    int e = beg + g;
    for (; e + 12 < end; e += 16) {
        int s0 = esrc[e], s1 = esrc[e + 4], s2 = esrc[e + 8], s3 = esrc[e + 12];
        const uint4 u0 = *reinterpret_cast<const uint4*>(src + (size_t)s0 * HD + c8);
        const uint4 u1 = *reinterpret_cast<const uint4*>(src + (size_t)s1 * HD + c8);
        const uint4 u2 = *reinterpret_cast<const uint4*>(src + (size_t)s2 * HD + c8);
        const uint4 u3 = *reinterpret_cast<const uint4*>(src + (size_t)s3 * HD + c8);
        acc0 += expand2(u0.x, u0.y); acc1 += expand2(u0.z, u0.w);
        acc0 += expand2(u1.x, u1.y); acc1 += expand2(u1.z, u1.w);
        acc0 += expand2(u2.x, u2.y); acc1 += expand2(u2.z, u2.w);
        acc0 += expand2(u3.x, u3.y); acc1 += expand2(u3.z, u3.w);
    }
    for (; e < end; e += 4) {
        const uint4 u0 = *reinterpret_cast<const uint4*>(src + (size_t)esrc[e] * HD + c8);
        acc0 += expand2(u0.x, u0.y); acc1 += expand2(u0.z, u0.w);
    }
    float s[8] = {acc0.x, acc0.y, acc0.z, acc0.w, acc1.x, acc1.y, acc1.z, acc1.w};
#pragma unroll
    for (int j = 0; j < 8; ++j) {
        float a = s[j];
        a += __shfl_xor(a, 16, 64);
        a += __shfl_xor(a, 32, 64);
        s[j] = a;
    }
    if (lane < 16) {
        uint4 u;
        u.x = (unsigned)f2bf_bits(s[0] * iv) | ((unsigned)f2bf_bits(s[1] * iv) << 16);
        u.y = (unsigned)f2bf_bits(s[2] * iv) | ((unsigned)f2bf_bits(s[3] * iv) << 16);
        u.z = (unsigned)f2bf_bits(s[4] * iv) | ((unsigned)f2bf_bits(s[5] * iv) << 16);
        u.w = (unsigned)f2bf_bits(s[6] * iv) | ((unsigned)f2bf_bits(s[7] * iv) << 16);
        *reinterpret_cast<uint4*>(outrow + c8) = u;
    }
}

__device__ __forceinline__ void agg_body(
    int bid, int tid,
    const bf16* __restrict__ srcA, const int* __restrict__ rbA, const int* __restrict__ reA,
    const bf16* __restrict__ srcB, const int* __restrict__ rbB, const int* __restrict__ reB,
    const int* __restrict__ esrc,
    bf16* __restrict__ outA, bf16* __restrict__ outB, int n)
{
    int node = (bid * 256 + tid) >> 6;
    if (node >= n) return;
    int lane = tid & 63;
    int c8 = (lane & 15) << 3;
    gather_reduce_store(srcA, esrc, rbA[node], reA[node], lane >> 4, c8, lane,
                        outA + (size_t)node * HD);
    if (srcB)
        gather_reduce_store(srcB, esrc, rbB[node], reB[node], lane >> 4, c8, lane,
                            outB + (size_t)node * HD);
}

// ============================================= MFMA GEMM body (hi+lo split weights)
__device__ __forceinline__ void gemm_body(
    int bid, int tid,
    const bf16* __restrict__ g1, const bf16* __restrict__ g2, const bf16* hsrc,
    const unsigned short* __restrict__ whi, const unsigned short* __restrict__ wlo,
    const float* __restrict__ b1, const float* __restrict__ b2,
    bf16* out, int n)
{
    const int wave = bid * 4 + (tid >> 6);
    const int rowBase = wave * 32;
    if (rowBase >= n) return;
    const int lane = tid & 63;
    const int lr = lane & 15;
    const int kg = lane >> 4;

    f32x4 acc[2][8];
#pragma unroll
    for (int m = 0; m < 2; ++m)
#pragma unroll
        for (int t = 0; t < 8; ++t) acc[m][t] = (f32x4){0.f, 0.f, 0.f, 0.f};

#pragma unroll
    for (int t = 0; t < 12; ++t) {
        const bf16* xs = (t < 4) ? g1 : ((t < 8) ? g2 : hsrc);
        const int kin = ((t & 3) << 5) + (kg << 3);
        short8 a0 = *reinterpret_cast<const short8*>(xs + (size_t)(rowBase + lr) * HD + kin);
        short8 a1 = *reinterpret_cast<const short8*>(xs + (size_t)(rowBase + 16 + lr) * HD + kin);
        const int kofs = (t << 5) + (kg << 3);
#pragma unroll
        for (int nt = 0; nt < 8; ++nt) {
            short8 bh = *reinterpret_cast<const short8*>(whi + (size_t)(nt * 16 + lr) * 384 + kofs);
            short8 bl = *reinterpret_cast<const short8*>(wlo + (size_t)(nt * 16 + lr) * 384 + kofs);
            acc[0][nt] = __builtin_amdgcn_mfma_f32_16x16x32_bf16(a0, bh, acc[0][nt], 0, 0, 0);
            acc[1][nt] = __builtin_amdgcn_mfma_f32_16x16x32_bf16(a1, bh, acc[1][nt], 0, 0, 0);
            acc[0][nt] = __builtin_amdgcn_mfma_f32_16x16x32_bf16(a0, bl, acc[0][nt], 0, 0, 0);
            acc[1][nt] = __builtin_amdgcn_mfma_f32_16x16x32_bf16(a1, bl, acc[1][nt], 0, 0, 0);
        }
    }

#pragma unroll
    for (int nt = 0; nt < 8; ++nt) {
        int c = nt * 16 + lr;
        float bias = b1[c] + b2[c];
#pragma unroll
        for (int m = 0; m < 2; ++m) {
#pragma unroll
            for (int r = 0; r < 4; ++r) {
                int row = rowBase + m * 16 + kg * 4 + r;
                float v = fmaxf(acc[m][nt][r] + bias, 0.0f);
                out[(size_t)row * HD + c] = __float2bfloat16(v);
            }
        }
    }
}

// ============================================= kernels (standalone + fused)
__global__ __launch_bounds__(256) void aggregate2_kernel(
    const bf16* srcA, const int* rbA, const int* reA,
    const bf16* srcB, const int* rbB, const int* reB,
    const int* esrc, bf16* outA, bf16* outB, int n)
{
    agg_body(blockIdx.x, threadIdx.x, srcA, rbA, reA, srcB, rbB, reB, esrc, outA, outB, n);
}

__global__ __launch_bounds__(256) void mfma_gemm(
    const bf16* g1, const bf16* g2, const bf16* hsrc,
    const unsigned short* whi, const unsigned short* wlo,
    const float* b1, const float* b2, bf16* out, int n)
{
    gemm_body(blockIdx.x, threadIdx.x, g1, g2, hsrc, whi, wlo, b1, b2, out, n);
}

__global__ __launch_bounds__(256) void gemm_agg_kernel(
    const bf16* g1, const bf16* g2, const bf16* hsrc,
    const unsigned short* whi, const unsigned short* wlo,
    const float* b1, const float* b2, bf16* gout,
    const bf16* srcA, const int* rbA, const int* reA,
    const bf16* srcB, const int* rbB, const int* reB,
    const int* esrc, bf16* outA, bf16* outB, int n, int gemmB)
{
    if ((int)blockIdx.x < gemmB)
        gemm_body(blockIdx.x, threadIdx.x, g1, g2, hsrc, whi, wlo, b1, b2, gout, n);
    else
        agg_body(blockIdx.x - gemmB, threadIdx.x, srcA, rbA, reA, srcB, rbB, reB, esrc, outA, outB, n);
}

// ============================================= decoder (OUT=3, bf16 h)
__global__ __launch_bounds__(128) void decoder_kernel(
    const bf16* __restrict__ hp, const bf16* __restrict__ hd,
    const float* __restrict__ wp, const float* __restrict__ bp,
    const float* __restrict__ wd, const float* __restrict__ bd,
    float* __restrict__ out, int n)
{
    int b = blockIdx.x;
    const bf16* h; const float* w; const float* bb; float* o;
    if (b < n) { h = hp + (size_t)b * HD; w = wp; bb = bp; o = out + (size_t)b * 3; }
    else { int nd = b - n; h = hd + (size_t)nd * HD; w = wd; bb = bd; o = out + (size_t)n * 3 + (size_t)nd * 3; }
    int t = threadIdx.x;
    float x = __bfloat162float(h[t]);
    float p0 = x * w[0 * HD + t];
    float p1 = x * w[1 * HD + t];
    float p2 = x * w[2 * HD + t];
#pragma unroll
    for (int off = 32; off > 0; off >>= 1) {
        p0 += __shfl_down(p0, off, 64);
        p1 += __shfl_down(p1, off, 64);
        p2 += __shfl_down(p2, off, 64);
    }
    __shared__ float red[2][3];
    if ((t & 63) == 0) { int wv = t >> 6; red[wv][0] = p0; red[wv][1] = p1; red[wv][2] = p2; }
    __syncthreads();
    if (t < 3) o[t] = red[0][t] + red[1][t] + bb[t];
}

// ============================================= launch
extern "C" void kernel_launch(void* const* d_in, const int* in_sizes, int n_in,
                              void* d_out, int out_size, void* d_ws, size_t ws_size,
                              hipStream_t stream)
{
    const float* x_p     = (const float*)d_in[0];
    const float* x_d     = (const float*)d_in[1];
    const int*   ei_pp   = (const int*)d_in[2];
    const int*   ei_dd   = (const int*)d_in[3];
    const int*   ei_p2d  = (const int*)d_in[4];
    const float* enc_p_w = (const float*)d_in[5];
    const float* enc_p_b = (const float*)d_in[6];
    const float* enc_d_w = (const float*)d_in[7];
    const float* enc_d_b = (const float*)d_in[8];
    const float* lin_l_w = (const float*)d_in[9];
    const float* lin_l_b = (const float*)d_in[10];
    const float* lin_r_w = (const float*)d_in[11];
    const float* dec_p_w = (const float*)d_in[12];
    const float* dec_p_b = (const float*)d_in[13];
    const float* dec_d_w = (const float*)d_in[14];
    const float* dec_d_b = (const float*)d_in[15];
    float* out = (float*)d_out;

    const int N = NN, E = EE;
    const size_t NHs = (size_t)N * HD;

    // ---- workspace (~222 MB): 7 bf16 feature buffers (rec overlays GC/GD) ----
    bf16* GA = (bf16*)d_ws;
    bf16* GB = GA + NHs;
    bf16* Hp = GB + NHs;
    bf16* Hd = Hp + NHs;
    bf16* Ht = Hd + NHs;
    bf16* GC = Ht + NHs;
    bf16* GD = GC + NHs;
    unsigned short* Whi = (unsigned short*)(GD + NHs);   // 4*128*384
    unsigned short* Wlo = Whi + 4 * 128 * 384;
    int*      ccursor = (int*)(Wlo + 4 * 128 * 384);      // NTB (zeroed each call)
    int*      rowbeg  = ccursor + NTB;                    // 4*N
    int*      rowend  = rowbeg + 4 * (size_t)N;           // 4*N
    int*      esrc    = rowend + 4 * (size_t)N;           // NTB*BCAP
    unsigned* rec     = (unsigned*)GC;                    // NTB*BCAP (dead after fill)

    #define BL(b_l, b_i) (lin_l_b + ((b_l) * 4 + (b_i)) * HD)
    #define WT(cfg) (Whi + (size_t)(cfg) * 128 * 384), (Wlo + (size_t)(cfg) * 128 * 384)

    const int* rb_pp  = rowbeg;
    const int* rb_dd  = rowbeg + N;
    const int* rb_p2d = rowbeg + 2 * (size_t)N;
    const int* rb_d2p = rowbeg + 3 * (size_t)N;
    const int* re_pp  = rowend;
    const int* re_dd  = rowend + N;
    const int* re_p2d = rowend + 2 * (size_t)N;
    const int* re_d2p = rowend + 3 * (size_t)N;

    const int AGG_B  = (N * 64 + 255) / 256;             // 25000
    const int GEMM_B = ((N + 31) / 32 + 3) / 4;          // 782

    // D1: zero bucket cursors
    hipMemsetAsync(ccursor, 0, NTB * sizeof(int), stream);
    // D2: scatter ∥ encoders (Hp, Hd)
    scatter_enc_kernel<<<SCAT_B + ENC_B, 1024, 0, stream>>>(
        ei_pp, ei_dd, ei_p2d, ccursor, rec,
        x_p, enc_p_w, enc_p_b, x_d, enc_d_w, enc_d_b, Hp, Hd, E, N);
    // D3: prep_w ∥ fill_stats
    fill_prep_kernel<<<PREP_B + NTB, 256, 0, stream>>>(
        rec, ccursor, rowbeg, rowend, esrc, lin_l_w, lin_r_w, Whi, Wlo, N);

    // ---------------- layer 0 ----------------
    // D4: agg (Hp,pp)->GA, (Hd,d2p)->GB
    aggregate2_kernel<<<AGG_B, 256, 0, stream>>>(Hp, rb_pp, re_pp, Hd, rb_d2p, re_d2p,
        esrc, GA, GB, N);
    // D5: gemm0 (GA,GB,Hp -> Ht) ∥ agg (Hd,dd)->GC, (Hp,p2d)->GD
    gemm_agg_kernel<<<GEMM_B + AGG_B, 256, 0, stream>>>(
        GA, GB, Hp, WT(0), BL(0, 0), BL(0, 3), Ht,
        Hd, rb_dd, re_dd, Hp, rb_p2d, re_p2d, esrc, GC, GD, N, GEMM_B);
    // D6: gemm1 (GC,GD,Hd -> Hd in-place) ∥ agg (Ht,pp)->GA  [layer-1 pp gather]
    gemm_agg_kernel<<<GEMM_B + AGG_B, 256, 0, stream>>>(
        GC, GD, Hd, WT(1), BL(0, 1), BL(0, 2), Hd,
        Ht, rb_pp, re_pp, (const bf16*)nullptr, nullptr, nullptr, esrc, GA, nullptr, N, GEMM_B);

    // ---------------- layer 1 ----------------
    // D7: agg (Hd,d2p)->GB   (needs new Hd from D6)
    aggregate2_kernel<<<AGG_B, 256, 0, stream>>>(Hd, rb_d2p, re_d2p,
        (const bf16*)nullptr, nullptr, nullptr, esrc, GB, nullptr, N);
    // D8: gemm2 (GA,GB,Ht -> Hp) ∥ agg (Hd,dd)->GC, (Ht,p2d)->GD
    gemm_agg_kernel<<<GEMM_B + AGG_B, 256, 0, stream>>>(
        GA, GB, Ht, WT(2), BL(1, 0), BL(1, 3), Hp,
        Hd, rb_dd, re_dd, Ht, rb_p2d, re_p2d, esrc, GC, GD, N, GEMM_B);
    // D9: gemm3 (GC,GD,Hd -> Hd in-place)
    mfma_gemm<<<GEMM_B, 256, 0, stream>>>(GC, GD, Hd, WT(3), BL(1, 1), BL(1, 2), Hd, N);

    // D10: decoders: primal from Hp, dual from Hd
    decoder_kernel<<<2 * N, 128, 0, stream>>>(Hp, Hd, dec_p_w, dec_p_b, dec_d_w, dec_d_b, out, N);

    #undef WT
    #undef BL
}